// Round 1
// baseline (722.732 us; speedup 1.0000x reference)
//
#include <hip/hip_runtime.h>

#define NTOT 4096
#define CCH  128
#define CQN  16
#define TI   64
#define TJ   64

// ---------------- q,k projection: q[b,cq,n] = sum_c wq[cq,c]*x[b,c,n] + bq ----
__global__ __launch_bounds__(256) void qk_proj(const float* __restrict__ x,
    const float* __restrict__ wq, const float* __restrict__ bq,
    const float* __restrict__ wk, const float* __restrict__ bk,
    float* __restrict__ qws, float* __restrict__ kws) {
  __shared__ float wq_s[CQN * CCH];
  __shared__ float wk_s[CQN * CCH];
  int t = threadIdx.x;
  for (int i = t; i < CQN * CCH; i += 256) { wq_s[i] = wq[i]; wk_s[i] = wk[i]; }
  __syncthreads();
  int gid = blockIdx.x * 256 + t;
  int b = gid >> 12;
  int n = gid & 4095;
  const float* xb = x + (size_t)b * CCH * NTOT + n;
  float aq[CQN], ak[CQN];
#pragma unroll
  for (int i = 0; i < CQN; i++) { aq[i] = bq[i]; ak[i] = bk[i]; }
  for (int c = 0; c < CCH; c++) {
    float xv = xb[(size_t)c * NTOT];
#pragma unroll
    for (int i = 0; i < CQN; i++) {
      aq[i] = fmaf(wq_s[i * CCH + c], xv, aq[i]);
      ak[i] = fmaf(wk_s[i * CCH + c], xv, ak[i]);
    }
  }
#pragma unroll
  for (int i = 0; i < CQN; i++) {
    qws[((size_t)b * CQN + i) * NTOT + n] = aq[i];
    kws[((size_t)b * CQN + i) * NTOT + n] = ak[i];
  }
}

// ---------------- v projection: v[b,o,n] = sum_c wv[o,c]*x[b,c,n] + bv --------
__global__ __launch_bounds__(256) void v_proj(const float* __restrict__ x,
    const float* __restrict__ wv, const float* __restrict__ bv,
    float* __restrict__ vws) {
  int blk = blockIdx.x;            // 256 blocks: b(4) x nt(32) x ch(2)
  int ch = blk & 1;
  int nt = (blk >> 1) & 31;
  int b  = blk >> 6;
  __shared__ float wv_s[64 * CCH]; // rows ch*64 .. ch*64+63
  int t = threadIdx.x;
  for (int i = t; i < 64 * CCH; i += 256) wv_s[i] = wv[(size_t)ch * 64 * CCH + i];
  __syncthreads();
  int n  = nt * 128 + (t & 127);
  int cg = t >> 7;                 // 0..1 -> 32 channels each
  const float* xb = x + (size_t)b * CCH * NTOT + n;
  float acc[32];
#pragma unroll
  for (int i = 0; i < 32; i++) acc[i] = bv[ch * 64 + cg * 32 + i];
  for (int c2 = 0; c2 < CCH; c2++) {
    float xv = xb[(size_t)c2 * NTOT];
#pragma unroll
    for (int i = 0; i < 32; i++)
      acc[i] = fmaf(wv_s[(cg * 32 + i) * CCH + c2], xv, acc[i]);
  }
#pragma unroll
  for (int i = 0; i < 32; i++)
    vws[((size_t)b * CCH + ch * 64 + cg * 32 + i) * NTOT + n] = acc[i];
}

// ---------------- flash attention + epilogue ---------------------------------
__global__ __launch_bounds__(256) void attn_kern(const float* __restrict__ qws,
    const float* __restrict__ kws, const float* __restrict__ vws,
    const float* __restrict__ x, const float* __restrict__ gamma_p,
    float* __restrict__ out) {
  // XCD-aware swizzle: g = (it>>1)*8 + 2b + (it&1)  -> each batch pinned to 2 XCDs
  int g = blockIdx.x;
  int r = g & 7;
  int b = r >> 1;
  int it = ((g >> 3) << 1) | (r & 1);
  int i0 = it * TI;

  __shared__ float k_s[CQN * TJ];           // [cq][jj]
  __shared__ float v_s[CCH * (TJ + 1)];     // [c][jj] stride 65 (conflict-free)
  __shared__ float e_s[TJ * (TI + 1)];      // [jj][ii] stride 65 (transposed P)
  __shared__ float corr_s[TI];
  __shared__ float l_s[TI];

  int t    = threadIdx.x;
  int ii_l = t & 63;   // energy: this thread's i-row
  int jjg  = t >> 6;   // energy: jj block of 16
  int iig  = t & 15;   // PV: ii group (4 rows)
  int cgr  = t >> 4;   // PV: c group (8 channels)

  const float* qb = qws + (size_t)b * CQN * NTOT;
  const float* kb = kws + (size_t)b * CQN * NTOT;
  const float* vb = vws + (size_t)b * CCH * NTOT;

  float q_reg[CQN];
#pragma unroll
  for (int cq = 0; cq < CQN; cq++) q_reg[cq] = qb[cq * NTOT + i0 + ii_l];

  float acc[4][8];
#pragma unroll
  for (int u = 0; u < 4; u++)
#pragma unroll
    for (int cc = 0; cc < 8; cc++) acc[u][cc] = 0.f;

  float m_reg = -1e30f, l_reg = 0.f;  // live only in wave 0

  for (int j0 = 0; j0 < NTOT; j0 += TJ) {
    // stage K tile (1024 f32)
    for (int i = t; i < CQN * TJ; i += 256) {
      int cq = i >> 6; int jj = i & 63;
      k_s[i] = kb[cq * NTOT + j0 + jj];
    }
    // stage V tile (8192 f32), coalesced rows
    {
      int jj = t & 63; int c0 = t >> 6;
      for (int cstep = 0; cstep < CCH; cstep += 4) {
        int c = cstep + c0;
        v_s[c * (TJ + 1) + jj] = vb[(size_t)c * NTOT + j0 + jj];
      }
    }
    __syncthreads();

    // energy: e[ii][jj'] for 16 jj's, K=16 dot from regs x LDS-broadcast
    float e_acc[16];
#pragma unroll
    for (int j = 0; j < 16; j++) e_acc[j] = 0.f;
#pragma unroll
    for (int cq = 0; cq < CQN; cq++) {
      float qv = q_reg[cq];
#pragma unroll
      for (int j = 0; j < 16; j++)
        e_acc[j] = fmaf(qv, k_s[cq * TJ + jjg * 16 + j], e_acc[j]);
    }
#pragma unroll
    for (int j = 0; j < 16; j++)
      e_s[(jjg * 16 + j) * (TI + 1) + ii_l] = e_acc[j];
    __syncthreads();

    // online softmax: wave 0, one lane per i-row (column reads, conflict-free)
    if (t < 64) {
      int ii = t;
      float mt = -1e30f;
      for (int jj = 0; jj < TJ; jj++) mt = fmaxf(mt, e_s[jj * (TI + 1) + ii]);
      float mnew = fmaxf(m_reg, mt);
      float corr = __expf(m_reg - mnew);
      float rsum = 0.f;
      for (int jj = 0; jj < TJ; jj++) {
        float p = __expf(e_s[jj * (TI + 1) + ii] - mnew);
        e_s[jj * (TI + 1) + ii] = p;
        rsum += p;
      }
      l_reg = l_reg * corr + rsum;
      m_reg = mnew;
      corr_s[ii] = corr;
    }
    __syncthreads();

    // PV accumulate: 4 ii x 8 c per thread -> 12 LDS reads / 32 FMA
    float corrv[4];
#pragma unroll
    for (int u = 0; u < 4; u++) corrv[u] = corr_s[iig * 4 + u];
#pragma unroll
    for (int u = 0; u < 4; u++)
#pragma unroll
      for (int cc = 0; cc < 8; cc++) acc[u][cc] *= corrv[u];
    for (int jj = 0; jj < TJ; jj++) {
      float pv[4];
#pragma unroll
      for (int u = 0; u < 4; u++) pv[u] = e_s[jj * (TI + 1) + iig * 4 + u];
#pragma unroll
      for (int cc = 0; cc < 8; cc++) {
        float vv = v_s[(cgr * 8 + cc) * (TJ + 1) + jj];
#pragma unroll
        for (int u = 0; u < 4; u++) acc[u][cc] = fmaf(pv[u], vv, acc[u][cc]);
      }
    }
    __syncthreads();  // e_s/v_s reused next iteration
  }

  if (t < 64) l_s[t] = l_reg;
  __syncthreads();

  float gamma = gamma_p[0];
  const float* xb = x + (size_t)b * CCH * NTOT;
  float* ob = out + (size_t)b * CCH * NTOT;
#pragma unroll
  for (int u = 0; u < 4; u++) {
    int i = i0 + iig * 4 + u;
    float linv = 1.f / l_s[iig * 4 + u];
#pragma unroll
    for (int cc = 0; cc < 8; cc++) {
      int c = cgr * 8 + cc;
      size_t idx = (size_t)c * NTOT + i;
      ob[idx] = gamma * (acc[u][cc] * linv) + xb[idx];
    }
  }
}

extern "C" void kernel_launch(void* const* d_in, const int* in_sizes, int n_in,
                              void* d_out, int out_size, void* d_ws, size_t ws_size,
                              hipStream_t stream) {
  const float* x     = (const float*)d_in[0];
  const float* wq    = (const float*)d_in[1];
  const float* bq    = (const float*)d_in[2];
  const float* wk    = (const float*)d_in[3];
  const float* bk    = (const float*)d_in[4];
  const float* wv    = (const float*)d_in[5];
  const float* bv    = (const float*)d_in[6];
  const float* gamma = (const float*)d_in[7];
  float* out = (float*)d_out;

  float* qws = (float*)d_ws;                 // 4*16*4096   = 262144 f32
  float* kws = qws + (size_t)4 * CQN * NTOT; // 262144 f32
  float* vws = kws + (size_t)4 * CQN * NTOT; // 4*128*4096  = 2097152 f32
                                             // total ~10.5 MB of d_ws

  qk_proj<<<64, 256, 0, stream>>>(x, wq, bq, wk, bk, qws, kws);
  v_proj<<<256, 256, 0, stream>>>(x, wv, bv, vws);
  attn_kern<<<256, 256, 0, stream>>>(qws, kws, vws, x, gamma, out);
}

// Round 2
// 72.163 us; speedup vs baseline: 10.0153x; 10.0153x over previous
//
#include <hip/hip_runtime.h>
#include <stdint.h>

#define NT 4096

typedef short s16x8 __attribute__((ext_vector_type(8)));
typedef short s16x4 __attribute__((ext_vector_type(4)));
typedef float f32x16 __attribute__((ext_vector_type(16)));
typedef float f32x4 __attribute__((ext_vector_type(4)));
typedef unsigned int u32x2 __attribute__((ext_vector_type(2)));

__device__ __forceinline__ unsigned short f2bf(float f) {
  unsigned int u = __float_as_uint(f);
  u = u + 0x7FFFu + ((u >> 16) & 1u);   // RNE to bf16
  return (unsigned short)(u >> 16);
}

// ============================================================================
// Fused projection GEMM: [wv(128); wq(16); wk(16)] @ x  ->  vws, qws_t, kws_t
// vws: bf16 [b][c][n] ; qws/kws: bf16 [b][n][16] (transposed for attn frags)
// ============================================================================
__global__ __launch_bounds__(256) void proj_kern(
    const float* __restrict__ x,
    const float* __restrict__ wq, const float* __restrict__ bq,
    const float* __restrict__ wk, const float* __restrict__ bk,
    const float* __restrict__ wv, const float* __restrict__ bv,
    short* __restrict__ qws, short* __restrict__ kws, short* __restrict__ vws) {
  __shared__ __align__(16) unsigned short w_s[160 * 128];  // rows 0-127 wv, 128-143 wq, 144-159 wk (swizzled)
  __shared__ __align__(16) unsigned short x_s[128 * 128];  // [c_in][n] bf16, linear

  int t = threadIdx.x;
  int blk = blockIdx.x;
  int b = blk >> 5;
  int n0 = (blk & 31) * 128;

  // stage weights (swizzle: byte-in-row ^= (row&7)<<4, 16B granules)
  for (int idx = t; idx < 128 * 128; idx += 256) {
    int c = idx >> 7, k = idx & 127;
    unsigned byt = ((unsigned)(k * 2)) ^ (((unsigned)c & 7u) << 4);
    w_s[c * 128 + (byt >> 1)] = f2bf(wv[idx]);
  }
  for (int idx = t; idx < 16 * 128; idx += 256) {
    int c = idx >> 7, k = idx & 127;
    int rq = 128 + c, rk = 144 + c;
    unsigned bq_ = ((unsigned)(k * 2)) ^ (((unsigned)rq & 7u) << 4);
    unsigned bk_ = ((unsigned)(k * 2)) ^ (((unsigned)rk & 7u) << 4);
    w_s[rq * 128 + (bq_ >> 1)] = f2bf(wq[idx]);
    w_s[rk * 128 + (bk_ >> 1)] = f2bf(wk[idx]);
  }
  // stage x tile [128 c_in][128 n]
  for (int idx = t; idx < 128 * 128; idx += 256) {
    int k = idx >> 7, nn = idx & 127;
    x_s[k * 128 + nn] = f2bf(x[((size_t)b * 128 + k) * NT + n0 + nn]);
  }
  __syncthreads();

  int w = t >> 6, lane = t & 63, lc = lane & 31, hi = lane >> 5;
  int nn = w * 32 + lc;                 // this lane's n column (within tile)

  f32x16 zf = {0.f,0.f,0.f,0.f,0.f,0.f,0.f,0.f,0.f,0.f,0.f,0.f,0.f,0.f,0.f,0.f};
  f32x16 acc[5];
#pragma unroll
  for (int i = 0; i < 5; ++i) acc[i] = zf;

#pragma unroll
  for (int kk = 0; kk < 8; ++kk) {
    // B fragment: x[k = kk*16 + 8*hi + e][nn]
    s16x8 xf;
    int kbase = kk * 16 + hi * 8;
#pragma unroll
    for (int e = 0; e < 8; ++e) xf[e] = (short)x_s[(kbase + e) * 128 + nn];
#pragma unroll
    for (int i = 0; i < 5; ++i) {
      int row = i * 32 + lc;
      unsigned byt = ((unsigned)(kk * 32 + hi * 16)) ^ (((unsigned)lc & 7u) << 4);
      s16x8 af = *(const s16x8*)(w_s + row * 128 + (byt >> 1));
      acc[i] = __builtin_amdgcn_mfma_f32_32x32x16_bf16(af, xf, acc[i], 0, 0, 0);
    }
  }

  // store V part: D[c_out][n], c_out = i*32 + (r&3)+8*(r>>2)+4*hi
#pragma unroll
  for (int i = 0; i < 4; ++i) {
#pragma unroll
    for (int r = 0; r < 16; ++r) {
      int c = i * 32 + (r & 3) + 8 * (r >> 2) + 4 * hi;
      float v = acc[i][r] + bv[c];
      vws[((size_t)b * 128 + c) * NT + n0 + nn] = (short)f2bf(v);
    }
  }
  // store q/k part (acc[4]): rows 0-15 = q, 16-31 = k
  {
    size_t nidx = ((size_t)b * NT + n0 + nn) * 16;
    s16x4 q0, q1, k0, k1;
#pragma unroll
    for (int j = 0; j < 4; ++j) {
      q0[j] = (short)f2bf(acc[4][j]      + bq[j + 4 * hi]);
      q1[j] = (short)f2bf(acc[4][j + 4]  + bq[j + 8 + 4 * hi]);
      k0[j] = (short)f2bf(acc[4][j + 8]  + bk[j + 4 * hi]);
      k1[j] = (short)f2bf(acc[4][j + 12] + bk[j + 8 + 4 * hi]);
    }
    *(s16x4*)(qws + nidx + 4 * hi)     = q0;
    *(s16x4*)(qws + nidx + 8 + 4 * hi) = q1;
    *(s16x4*)(kws + nidx + 4 * hi)     = k0;
    *(s16x4*)(kws + nidx + 8 + 4 * hi) = k1;
  }
}

// ============================================================================
// Flash attention, MFMA 32x32x16 bf16, swapped QK^T; 2 j-streams x 2 i-subs.
// ============================================================================
__device__ __forceinline__ void dsw(unsigned char* dbuf, int cs, int jq, s16x8 vv, int kofs) {
  int c = cs + kofs;
  unsigned char* rowp = dbuf + c * 64;
  unsigned sw = (((unsigned)c & 7u)) << 3;
  union U { s16x8 v; u32x2 h[2]; } uu; uu.v = vv;
  *(u32x2*)(rowp + (((unsigned)(jq * 16)) ^ sw))     = uu.h[0];
  *(u32x2*)(rowp + (((unsigned)(jq * 16 + 8)) ^ sw)) = uu.h[1];
}

__device__ __forceinline__ f32x16 pv_step(const unsigned char* cbuf, int cb, int sl,
                                          int lc, int hi, int swz, s16x8 pb, f32x16 a) {
  const unsigned char* rp = cbuf + (cb * 32 + lc) * 64;
  u32x2 h0 = *(const u32x2*)(rp + (((unsigned)(sl * 32 + hi * 8)) ^ (unsigned)swz));
  u32x2 h1 = *(const u32x2*)(rp + (((unsigned)(sl * 32 + 16 + hi * 8)) ^ (unsigned)swz));
  union U { u32x2 h[2]; s16x8 v; } uu; uu.h[0] = h0; uu.h[1] = h1;
  return __builtin_amdgcn_mfma_f32_32x32x16_bf16(uu.v, pb, a, 0, 0, 0);
}

__global__ __launch_bounds__(256) void attn_mfma(
    const short* __restrict__ qws, const short* __restrict__ kws, const short* __restrict__ vws,
    const float* __restrict__ x, const float* __restrict__ gp, float* __restrict__ out) {
  __shared__ __align__(16) unsigned char lds[33280];
  // [0,32768): V tiles (stream s, parity p) at (s*2+p)*8192 ; merge scratch overlays
  // [32768,+256): m[2][32] ; [+256,+512): l[2][32]

  int g = blockIdx.x;
  int gg = (g & 7) * 32 + (g >> 3);   // XCD swizzle: 2 XCDs per batch
  int b = gg >> 6;
  int it = gg & 63;
  int t = threadIdx.x;
  int w = t >> 6;
  int lane = t & 63;
  int lc = lane & 31;
  int hi = lane >> 5;
  int s = w >> 1;        // j-stream
  int isub = w & 1;      // i sub-block
  int i0 = it * 64 + isub * 32;
  int swz = (lane & 7) << 3;

  const short* qb = qws + (size_t)b * NT * 16;
  const short* kb = kws + (size_t)b * NT * 16;
  const short* vb = vws + (size_t)b * 128 * NT;

  // Q fragment (B-operand), fixed for whole kernel
  s16x8 qf = *(const s16x8*)(qb + (size_t)(i0 + lc) * 16 + hi * 8);

  f32x16 zf = {0.f,0.f,0.f,0.f,0.f,0.f,0.f,0.f,0.f,0.f,0.f,0.f,0.f,0.f,0.f,0.f};
  f32x16 acc[4];
#pragma unroll
  for (int i = 0; i < 4; ++i) acc[i] = zf;
  float m_l = -1e30f, l_l = 0.0f;

  int jbase = s * 2048;
  int tp = t & 127;
  int cs = tp >> 2;   // 0..31
  int jq = tp & 3;

  unsigned char* vbase = lds + s * 16384;

  // prologue: stage tile 0 -> buf 0 ; prefetch k frag for step 0
  {
    const short* src = vb + (size_t)cs * NT + jbase + jq * 8;
    s16x8 v0 = *(const s16x8*)(src);
    s16x8 v1 = *(const s16x8*)(src + (size_t)32 * NT);
    s16x8 v2 = *(const s16x8*)(src + (size_t)64 * NT);
    s16x8 v3 = *(const s16x8*)(src + (size_t)96 * NT);
    dsw(vbase, cs, jq, v0, 0);  dsw(vbase, cs, jq, v1, 32);
    dsw(vbase, cs, jq, v2, 64); dsw(vbase, cs, jq, v3, 96);
  }
  s16x8 kf = *(const s16x8*)(kb + (size_t)(jbase + lc) * 16 + hi * 8);
  __syncthreads();

  for (int st = 0; st < 64; ++st) {
    unsigned char* cbuf = vbase + (st & 1) * 8192;
    unsigned char* nbuf = vbase + ((st & 1) ^ 1) * 8192;
    s16x8 vl0 = kf, vl1 = kf, vl2 = kf, vl3 = kf, kn = kf;
    if (st < 63) {   // prefetch next tile (global -> regs) + next K frag
      const short* src = vb + (size_t)cs * NT + (jbase + (st + 1) * 32) + jq * 8;
      vl0 = *(const s16x8*)(src);
      vl1 = *(const s16x8*)(src + (size_t)32 * NT);
      vl2 = *(const s16x8*)(src + (size_t)64 * NT);
      vl3 = *(const s16x8*)(src + (size_t)96 * NT);
      kn = *(const s16x8*)(kb + (size_t)(jbase + (st + 1) * 32 + lc) * 16 + hi * 8);
    }

    // QK^T (swapped): e[r] = E[j0+crow(r,hi)][i0+lc]
    f32x16 e = __builtin_amdgcn_mfma_f32_32x32x16_bf16(kf, qf, zf, 0, 0, 0);

    // online softmax (lane-local + one shfl over the i-partner half)
    float mt = e[0];
#pragma unroll
    for (int r = 1; r < 16; ++r) mt = fmaxf(mt, e[r]);
    mt = fmaxf(mt, __shfl_xor(mt, 32));
    if (__any(mt > m_l + 8.0f)) {        // defer-rescale (T13)
      float mnew = fmaxf(m_l, mt);
      float corr = __expf(m_l - mnew);
      l_l *= corr;
      acc[0] *= corr; acc[1] *= corr; acc[2] *= corr; acc[3] *= corr;
      m_l = mnew;
    }
    float p[16]; float rs = 0.f;
#pragma unroll
    for (int r = 0; r < 16; ++r) { p[r] = __expf(e[r] - m_l); rs += p[r]; }
    rs += __shfl_xor(rs, 32);
    l_l += rs;

    s16x8 pb0, pb1;
#pragma unroll
    for (int r = 0; r < 8; ++r) { pb0[r] = (short)f2bf(p[r]); pb1[r] = (short)f2bf(p[r + 8]); }

    // PV: sigma-permuted k-slices -> P frag needs no cross-lane exchange
#pragma unroll
    for (int i = 0; i < 4; ++i) acc[i] = pv_step(cbuf, i, 0, lc, hi, swz, pb0, acc[i]);
#pragma unroll
    for (int i = 0; i < 4; ++i) acc[i] = pv_step(cbuf, i, 1, lc, hi, swz, pb1, acc[i]);

    if (st < 63) {   // write prefetched tile to the other buffer
      dsw(nbuf, cs, jq, vl0, 0);  dsw(nbuf, cs, jq, vl1, 32);
      dsw(nbuf, cs, jq, vl2, 64); dsw(nbuf, cs, jq, vl3, 96);
    }
    kf = kn;
    __syncthreads();
  }

  // merge the two j-streams, then epilogue
  f32x4* scr = (f32x4*)lds;
  float* mlm = (float*)(lds + 32768);
  float* mll = (float*)(lds + 32768 + 256);
  if (s == 1) {
#pragma unroll
    for (int i = 0; i < 4; ++i)
#pragma unroll
      for (int rq = 0; rq < 4; ++rq) {
        f32x4 v4 = { acc[i][4*rq], acc[i][4*rq+1], acc[i][4*rq+2], acc[i][4*rq+3] };
        scr[((isub * 16 + i * 4 + rq) * 64) + lane] = v4;
      }
    if (hi == 0) { mlm[isub * 32 + lc] = m_l; mll[isub * 32 + lc] = l_l; }
  }
  __syncthreads();
  if (s == 0) {
    float mB = mlm[isub * 32 + lc], lB = mll[isub * 32 + lc];
    float mF = fmaxf(m_l, mB);
    float ca = __expf(m_l - mF), cb2 = __expf(mB - mF);
    float lf = l_l * ca + lB * cb2;
    float inv = 1.0f / lf;
    float gam = gp[0];
    const float* xb = x + (size_t)b * 128 * NT + i0 + lc;
    float* ob = out + (size_t)b * 128 * NT + i0 + lc;
#pragma unroll
    for (int i = 0; i < 4; ++i)
#pragma unroll
      for (int rq = 0; rq < 4; ++rq) {
        f32x4 o4 = scr[((isub * 16 + i * 4 + rq) * 64) + lane];
#pragma unroll
        for (int j = 0; j < 4; ++j) {
          int r = rq * 4 + j;
          int c = i * 32 + (r & 3) + 8 * (r >> 2) + 4 * hi;
          size_t idx = (size_t)c * NT;
          float o = (acc[i][r] * ca + o4[j] * cb2) * inv;
          ob[idx] = gam * o + xb[idx];
        }
      }
  }
}

extern "C" void kernel_launch(void* const* d_in, const int* in_sizes, int n_in,
                              void* d_out, int out_size, void* d_ws, size_t ws_size,
                              hipStream_t stream) {
  const float* x     = (const float*)d_in[0];
  const float* wq    = (const float*)d_in[1];
  const float* bq    = (const float*)d_in[2];
  const float* wk    = (const float*)d_in[3];
  const float* bk    = (const float*)d_in[4];
  const float* wv    = (const float*)d_in[5];
  const float* bv    = (const float*)d_in[6];
  const float* gamma = (const float*)d_in[7];
  float* out = (float*)d_out;

  short* qws = (short*)d_ws;                       // 4*4096*16 bf16 = 512 KB
  short* kws = qws + (size_t)4 * NT * 16;          // 512 KB
  short* vws = kws + (size_t)4 * NT * 16;          // 4*128*4096 bf16 = 4 MB

  proj_kern<<<128, 256, 0, stream>>>(x, wq, bq, wk, bk, wv, bv, qws, kws, vws);
  attn_mfma<<<256, 256, 0, stream>>>(qws, kws, vws, x, gamma, out);
}